// Round 10
// baseline (487.017 us; speedup 1.0000x reference)
//
#include <hip/hip_runtime.h>
#include <math.h>

#define NPOINTS (1 << 21)
#define LVL 16
#define TSIZE (1 << 19)
#define TMASK (TSIZE - 1)
#define PRIME2 2654435761u

typedef float f32x2 __attribute__((ext_vector_type(2)));
typedef float f32x4 __attribute__((ext_vector_type(4)));

struct ResArr {
    int   n[LVL];
    float fn[LVL];
};

// Plain 4-gather bilinear lookup (used by fallback).
__device__ __forceinline__ f32x2 level_feat(const f32x2* __restrict__ tables,
                                            int l, int N, float fN, f32x2 pt)
{
    float sx = pt.x * fN;
    float sy = pt.y * fN;
    float fx = floorf(sx);
    float fy = floorf(sy);
    float wx = sx - fx;
    float wy = sy - fy;
    int ix = (int)fx;
    int iy = (int)fy;

    int cx0 = (ix     >= N) ? ix - N     : ix;
    int cx1 = (ix + 1 >= N) ? ix + 1 - N : ix + 1;
    int cy0 = (iy     >= N) ? iy - N     : iy;
    int cy1 = (iy + 1 >= N) ? iy + 1 - N : iy + 1;

    unsigned hy0 = (unsigned)cy0 * PRIME2;
    unsigned hy1 = (unsigned)cy1 * PRIME2;

    const f32x2* tbl = tables + (size_t)l * TSIZE;
    f32x2 c00 = tbl[(int)(((unsigned)cx0 ^ hy0) & TMASK)];
    f32x2 c10 = tbl[(int)(((unsigned)cx1 ^ hy0) & TMASK)];
    f32x2 c01 = tbl[(int)(((unsigned)cx0 ^ hy1) & TMASK)];
    f32x2 c11 = tbl[(int)(((unsigned)cx1 ^ hy1) & TMASK)];

    float omx = 1.0f - wx, omy = 1.0f - wy;
    float f0x = c00.x * omx + c10.x * wx;
    float f0y = c00.y * omx + c10.y * wx;
    float f1x = c01.x * omx + c11.x * wx;
    float f1y = c01.y * omx + c11.y * wx;

    f32x2 r;
    r.x = f0x * omy + f1x * wy;
    r.y = f0y * omy + f1y * wy;
    return r;
}

// Pair-trick lookup: h = cx ^ (cy*PRIME) => for even, un-wrapped cx0 the two
// x-corners are the 16B-aligned entry pair {h&~1, h|1}. One dwordx4 serves
// both; only odd/wrapped lanes (~51%) issue the extra 8B loads (exec-masked
// => no TCP requests from inactive lanes). Lane-requests: 4 -> ~3.03.
__device__ __forceinline__ f32x2 level_feat_pair(const f32x2* __restrict__ tables,
                                                 int l, int N, float fN, f32x2 pt)
{
    float sx = pt.x * fN;
    float sy = pt.y * fN;
    float fx = floorf(sx);
    float fy = floorf(sy);
    float wx = sx - fx;
    float wy = sy - fy;
    int ix = (int)fx;
    int iy = (int)fy;

    int cx0 = (ix     >= N) ? ix - N     : ix;
    int cx1 = (ix + 1 >= N) ? ix + 1 - N : ix + 1;
    int cy0 = (iy     >= N) ? iy - N     : iy;
    int cy1 = (iy + 1 >= N) ? iy + 1 - N : iy + 1;

    unsigned hy0 = (unsigned)cy0 * PRIME2;
    unsigned hy1 = (unsigned)cy1 * PRIME2;
    unsigned h00 = ((unsigned)cx0 ^ hy0) & TMASK;
    unsigned h10 = ((unsigned)cx1 ^ hy0) & TMASK;
    unsigned h01 = ((unsigned)cx0 ^ hy1) & TMASK;
    unsigned h11 = ((unsigned)cx1 ^ hy1) & TMASK;

    const f32x2* tbl = tables + (size_t)l * TSIZE;

    f32x4 P0 = *(const f32x4*)(tbl + (h00 & ~1u));
    f32x4 P1 = *(const f32x4*)(tbl + (h01 & ~1u));

    bool o0 = (h00 & 1u);
    bool o1 = (h01 & 1u);
    f32x2 c00 = o0 ? (f32x2){P0.z, P0.w} : (f32x2){P0.x, P0.y};
    f32x2 c10 = o0 ? (f32x2){P0.x, P0.y} : (f32x2){P0.z, P0.w};
    f32x2 c01 = o1 ? (f32x2){P1.z, P1.w} : (f32x2){P1.x, P1.y};
    f32x2 c11 = o1 ? (f32x2){P1.x, P1.y} : (f32x2){P1.z, P1.w};

    if ((cx0 & 1) || (cx1 != cx0 + 1)) {   // odd or wrapped: true x1 fetch
        c10 = tbl[h10];
        c11 = tbl[h11];
    }

    float omx = 1.0f - wx, omy = 1.0f - wy;
    float f0x = c00.x * omx + c10.x * wx;
    float f0y = c00.y * omx + c10.y * wx;
    float f1x = c01.x * omx + c11.x * wx;
    float f1y = c01.y * omx + c11.y * wx;

    f32x2 r;
    r.x = f0x * omy + f1x * wy;
    r.y = f0y * omy + f1y * wy;
    return r;
}

// ---- Pass 1: level-phased gather (R9 structure, proven: FETCH 1.08GB->137MB)
// + pair-trick to cut TCP lane-requests ~24% now that pass1 is request-bound.
__global__ __launch_bounds__(256) void pass1_kernel(
    const f32x2* __restrict__ xy,
    const f32x2* __restrict__ tables,
    f32x2* __restrict__ ws,
    ResArr res)
{
    int tid = threadIdx.x;
    int j   = blockIdx.y;                    // phase 0..7
    int p0  = blockIdx.x * 1024 + tid;

    int   Na = res.n[j],     Nb = res.n[j + 8];
    float fa = res.fn[j],    fb = res.fn[j + 8];

    #pragma unroll
    for (int i = 0; i < 4; ++i) {
        int p = p0 + i * 256;
        f32x2 pt = __builtin_nontemporal_load(&xy[p]);

        f32x2 ra = level_feat_pair(tables, j,     Na, fa, pt);
        f32x2 rb = level_feat_pair(tables, j + 8, Nb, fb, pt);

        __builtin_nontemporal_store(ra, &ws[(size_t)j       * NPOINTS + p]);
        __builtin_nontemporal_store(rb, &ws[(size_t)(j + 8) * NPOINTS + p]);
    }
}

// ---- Pass 2: transpose ws (level-major) -> out (point-major). 5.9 TB/s
// measured (HBM stream ceiling) -- unchanged.
__global__ __launch_bounds__(256) void pass2_kernel(
    const f32x2* __restrict__ ws,
    f32x4* __restrict__ out)
{
    __shared__ f32x4 lds[256 * 9];
    int tid = threadIdx.x;
    int p   = blockIdx.x * 256 + tid;

    #pragma unroll
    for (int c = 0; c < 8; ++c) {
        f32x2 a = __builtin_nontemporal_load(&ws[(size_t)(2 * c)     * NPOINTS + p]);
        f32x2 b = __builtin_nontemporal_load(&ws[(size_t)(2 * c + 1) * NPOINTS + p]);
        f32x4 v = { a.x, a.y, b.x, b.y };
        lds[tid * 9 + c] = v;
    }
    __syncthreads();

    size_t base = (size_t)blockIdx.x * 2048;
    #pragma unroll
    for (int i = 0; i < 8; ++i) {
        int g = i * 256 + tid;
        f32x4 v = lds[(g >> 3) * 9 + (g & 7)];
        __builtin_nontemporal_store(v, &out[base + g]);
    }
}

// ---- Fallback (ws too small): single-pass kernel (~433 us).
__global__ __launch_bounds__(256, 6) void hashgrid2d_fallback(
    const f32x2* __restrict__ xy,
    const f32x2* __restrict__ tables,
    f32x4* __restrict__ out,
    ResArr res)
{
    __shared__ f32x4 lds[256 * 5];

    int tid = threadIdx.x;
    int p   = blockIdx.x * 256 + tid;

    f32x2 pt = __builtin_nontemporal_load(&xy[p]);
    size_t base = (size_t)blockIdx.x * 2048;

    #pragma unroll
    for (int b = 0; b < 2; ++b) {
        #pragma unroll
        for (int q = 0; q < 4; ++q) {
            float f[4];
            #pragma unroll
            for (int j = 0; j < 2; ++j) {
                int l = b * 8 + q * 2 + j;
                f32x2 r = level_feat(tables, l, res.n[l], res.fn[l], pt);
                f[j * 2 + 0] = r.x;
                f[j * 2 + 1] = r.y;
            }
            f32x4 v = { f[0], f[1], f[2], f[3] };
            lds[tid * 5 + q] = v;
        }
        __syncthreads();
        #pragma unroll
        for (int i = 0; i < 4; ++i) {
            int e  = i * 256 + tid;
            int pp = e >> 2;
            int q  = e & 3;
            f32x4 v = lds[pp * 5 + q];
            __builtin_nontemporal_store(v, &out[base + pp * 8 + b * 4 + q]);
        }
        __syncthreads();
    }
}

extern "C" void kernel_launch(void* const* d_in, const int* in_sizes, int n_in,
                              void* d_out, int out_size, void* d_ws, size_t ws_size,
                              hipStream_t stream) {
    const f32x2* xy     = (const f32x2*)d_in[0];
    const f32x2* tables = (const f32x2*)d_in[1];
    f32x4* out = (f32x4*)d_out;

    ResArr res;
    double b = pow(2048.0 / 16.0, 1.0 / 15.0);
    for (int l = 0; l < LVL; ++l) {
        int N = (int)llround(16.0 * pow(b, (double)l));
        res.n[l]  = N;
        res.fn[l] = (float)N;
    }

    const size_t WS_NEED = (size_t)LVL * NPOINTS * sizeof(f32x2);  // 256 MiB

    if (ws_size >= WS_NEED) {
        f32x2* ws = (f32x2*)d_ws;
        dim3 g1(NPOINTS / 1024, 8);
        pass1_kernel<<<g1, 256, 0, stream>>>(xy, tables, ws, res);
        pass2_kernel<<<NPOINTS / 256, 256, 0, stream>>>(ws, out);
    } else {
        hashgrid2d_fallback<<<NPOINTS / 256, 256, 0, stream>>>(xy, tables, out, res);
    }
}

// Round 11
// 397.330 us; speedup vs baseline: 1.2257x; 1.2257x over previous
//
#include <hip/hip_runtime.h>
#include <math.h>

#define NPOINTS (1 << 21)
#define LVL 16
#define TSIZE (1 << 19)
#define TMASK (TSIZE - 1)
#define PRIME2 2654435761u

// Morton bucket grid: 512 x 512 = 2^18 bins
#define GBITS 9
#define GRES (1 << GBITS)
#define NBINS (1 << (2 * GBITS))
#define SCAN_CHUNK 1024
#define NCHUNKS (NBINS / SCAN_CHUNK)   // 256

typedef float f32x2 __attribute__((ext_vector_type(2)));
typedef float f32x4 __attribute__((ext_vector_type(4)));

struct ResArr {
    int   n[LVL];
    float fn[LVL];
};

__device__ __forceinline__ unsigned part1by1(unsigned v) {
    v &= 0xFFFFu;
    v = (v | (v << 8)) & 0x00FF00FFu;
    v = (v | (v << 4)) & 0x0F0F0F0Fu;
    v = (v | (v << 2)) & 0x33333333u;
    v = (v | (v << 1)) & 0x55555555u;
    return v;
}

__device__ __forceinline__ unsigned morton_key(f32x2 pt) {
    int kx = (int)(pt.x * (float)GRES);
    int ky = (int)(pt.y * (float)GRES);
    kx = min(max(kx, 0), GRES - 1);
    ky = min(max(ky, 0), GRES - 1);
    return (part1by1((unsigned)ky) << 1) | part1by1((unsigned)kx);
}

// Plain 4-gather bilinear lookup (bit-identical to reference math).
__device__ __forceinline__ f32x2 level_feat(const f32x2* __restrict__ tables,
                                            int l, int N, float fN, f32x2 pt)
{
    float sx = pt.x * fN;
    float sy = pt.y * fN;
    float fx = floorf(sx);
    float fy = floorf(sy);
    float wx = sx - fx;
    float wy = sy - fy;
    int ix = (int)fx;
    int iy = (int)fy;

    int cx0 = (ix     >= N) ? ix - N     : ix;
    int cx1 = (ix + 1 >= N) ? ix + 1 - N : ix + 1;
    int cy0 = (iy     >= N) ? iy - N     : iy;
    int cy1 = (iy + 1 >= N) ? iy + 1 - N : iy + 1;

    unsigned hy0 = (unsigned)cy0 * PRIME2;
    unsigned hy1 = (unsigned)cy1 * PRIME2;

    const f32x2* tbl = tables + (size_t)l * TSIZE;
    f32x2 c00 = tbl[(int)(((unsigned)cx0 ^ hy0) & TMASK)];
    f32x2 c10 = tbl[(int)(((unsigned)cx1 ^ hy0) & TMASK)];
    f32x2 c01 = tbl[(int)(((unsigned)cx0 ^ hy1) & TMASK)];
    f32x2 c11 = tbl[(int)(((unsigned)cx1 ^ hy1) & TMASK)];

    float omx = 1.0f - wx, omy = 1.0f - wy;
    float f0x = c00.x * omx + c10.x * wx;
    float f0y = c00.y * omx + c10.y * wx;
    float f1x = c01.x * omx + c11.x * wx;
    float f1y = c01.y * omx + c11.y * wx;

    f32x2 r;
    r.x = f0x * omy + f1x * wy;
    r.y = f0y * omy + f1y * wy;
    return r;
}

// ---- Sort step 1: histogram of Morton keys.
__global__ __launch_bounds__(256) void hist_kernel(
    const f32x2* __restrict__ xy, unsigned* __restrict__ hist)
{
    int p = blockIdx.x * 256 + threadIdx.x;
    f32x2 pt = __builtin_nontemporal_load(&xy[p]);
    atomicAdd(&hist[morton_key(pt)], 1u);
}

// ---- Sort step 2a: per-chunk exclusive scan (1024 bins/chunk), chunk totals.
__global__ __launch_bounds__(SCAN_CHUNK) void scan_local_kernel(
    unsigned* __restrict__ hist, unsigned* __restrict__ aux)
{
    __shared__ unsigned s[SCAN_CHUNK];
    int t = threadIdx.x;
    int i = blockIdx.x * SCAN_CHUNK + t;
    unsigned v = hist[i];
    s[t] = v;
    __syncthreads();
    #pragma unroll
    for (int o = 1; o < SCAN_CHUNK; o <<= 1) {
        unsigned x = (t >= o) ? s[t - o] : 0u;
        __syncthreads();
        s[t] += x;
        __syncthreads();
    }
    hist[i] = s[t] - v;                       // exclusive within chunk
    if (t == SCAN_CHUNK - 1) aux[blockIdx.x] = s[t];  // chunk total
}

// ---- Sort step 2b: exclusive scan of the 256 chunk totals.
__global__ __launch_bounds__(NCHUNKS) void scan_aux_kernel(unsigned* __restrict__ aux)
{
    __shared__ unsigned s[NCHUNKS];
    int t = threadIdx.x;
    unsigned v = aux[t];
    s[t] = v;
    __syncthreads();
    #pragma unroll
    for (int o = 1; o < NCHUNKS; o <<= 1) {
        unsigned x = (t >= o) ? s[t - o] : 0u;
        __syncthreads();
        s[t] += x;
        __syncthreads();
    }
    aux[t] = s[t] - v;
}

// ---- Sort step 2c: add chunk offsets -> global exclusive offsets.
__global__ __launch_bounds__(SCAN_CHUNK) void scan_add_kernel(
    unsigned* __restrict__ hist, const unsigned* __restrict__ aux)
{
    int i = blockIdx.x * SCAN_CHUNK + threadIdx.x;
    hist[i] += aux[blockIdx.x];
}

// ---- Sort step 3: scatter points to bucket-sorted order.
__global__ __launch_bounds__(256) void scatter_kernel(
    const f32x2* __restrict__ xy, unsigned* __restrict__ off,
    f32x2* __restrict__ sxy, unsigned* __restrict__ oidx)
{
    int p = blockIdx.x * 256 + threadIdx.x;
    f32x2 pt = __builtin_nontemporal_load(&xy[p]);
    unsigned pos = atomicAdd(&off[morton_key(pt)], 1u);
    sxy[pos]  = pt;
    oidx[pos] = (unsigned)p;
}

// ---- Main: spatially-ordered gather, all 16 levels, direct full-line output.
// Wave lanes are Morton-adjacent -> corner gathers collapse to few distinct
// lines per instruction (TCP same-line coalescing) + heavy L1/L2 line reuse.
// Epilogue: two chunks of 8 levels = one full 64B line each (4x dwordx4 from
// the owning lane) -> no partial-line write amp, no ws round-trip, no pass2.
__global__ __launch_bounds__(256) void main_kernel(
    const f32x2* __restrict__ sxy,
    const unsigned* __restrict__ oidx,
    const f32x2* __restrict__ tables,
    f32x4* __restrict__ out,
    ResArr res)
{
    int sp = blockIdx.x * 256 + threadIdx.x;
    f32x2 pt = sxy[sp];
    unsigned op = oidx[sp];
    f32x4* o = out + (size_t)op * 8;

    #pragma unroll
    for (int hb = 0; hb < 2; ++hb) {          // 8 levels = one 64B out line
        f32x2 r[8];
        #pragma unroll
        for (int j = 0; j < 8; ++j) {
            int l = hb * 8 + j;
            r[j] = level_feat(tables, l, res.n[l], res.fn[l], pt);
        }
        #pragma unroll
        for (int q = 0; q < 4; ++q) {
            f32x4 v = { r[2 * q].x, r[2 * q].y, r[2 * q + 1].x, r[2 * q + 1].y };
            o[hb * 4 + q] = v;                // plain store: L2 merges the line
        }
    }
}

// ---- Fallback (ws too small): single-pass kernel (~433 us).
__global__ __launch_bounds__(256, 6) void hashgrid2d_fallback(
    const f32x2* __restrict__ xy,
    const f32x2* __restrict__ tables,
    f32x4* __restrict__ out,
    ResArr res)
{
    __shared__ f32x4 lds[256 * 5];

    int tid = threadIdx.x;
    int p   = blockIdx.x * 256 + tid;

    f32x2 pt = __builtin_nontemporal_load(&xy[p]);
    size_t base = (size_t)blockIdx.x * 2048;

    #pragma unroll
    for (int b = 0; b < 2; ++b) {
        #pragma unroll
        for (int q = 0; q < 4; ++q) {
            float f[4];
            #pragma unroll
            for (int j = 0; j < 2; ++j) {
                int l = b * 8 + q * 2 + j;
                f32x2 r = level_feat(tables, l, res.n[l], res.fn[l], pt);
                f[j * 2 + 0] = r.x;
                f[j * 2 + 1] = r.y;
            }
            f32x4 v = { f[0], f[1], f[2], f[3] };
            lds[tid * 5 + q] = v;
        }
        __syncthreads();
        #pragma unroll
        for (int i = 0; i < 4; ++i) {
            int e  = i * 256 + tid;
            int pp = e >> 2;
            int q  = e & 3;
            f32x4 v = lds[pp * 5 + q];
            __builtin_nontemporal_store(v, &out[base + pp * 8 + b * 4 + q]);
        }
        __syncthreads();
    }
}

extern "C" void kernel_launch(void* const* d_in, const int* in_sizes, int n_in,
                              void* d_out, int out_size, void* d_ws, size_t ws_size,
                              hipStream_t stream) {
    const f32x2* xy     = (const f32x2*)d_in[0];
    const f32x2* tables = (const f32x2*)d_in[1];
    f32x4* out = (f32x4*)d_out;

    ResArr res;
    double b = pow(2048.0 / 16.0, 1.0 / 15.0);
    for (int l = 0; l < LVL; ++l) {
        int N = (int)llround(16.0 * pow(b, (double)l));
        res.n[l]  = N;
        res.fn[l] = (float)N;
    }

    // ws layout: hist 1MiB | aux 1KiB (@1MiB) | sorted_xy 16MiB (@2MiB) |
    //            orig idx 8MiB (@18MiB)  -> need 26MiB
    const size_t WS_NEED = 26u << 20;

    if (ws_size >= WS_NEED) {
        char* w = (char*)d_ws;
        unsigned* hist = (unsigned*)(w);
        unsigned* aux  = (unsigned*)(w + (1u << 20));
        f32x2*    sxy  = (f32x2*)   (w + (2u << 20));
        unsigned* oidx = (unsigned*)(w + (18u << 20));

        hipMemsetAsync(hist, 0, NBINS * sizeof(unsigned), stream);
        hist_kernel      <<<NPOINTS / 256, 256,        0, stream>>>(xy, hist);
        scan_local_kernel<<<NCHUNKS,       SCAN_CHUNK, 0, stream>>>(hist, aux);
        scan_aux_kernel  <<<1,             NCHUNKS,    0, stream>>>(aux);
        scan_add_kernel  <<<NCHUNKS,       SCAN_CHUNK, 0, stream>>>(hist, aux);
        scatter_kernel   <<<NPOINTS / 256, 256,        0, stream>>>(xy, hist, sxy, oidx);
        main_kernel      <<<NPOINTS / 256, 256,        0, stream>>>(sxy, oidx, tables, out, res);
    } else {
        hashgrid2d_fallback<<<NPOINTS / 256, 256, 0, stream>>>(xy, tables, out, res);
    }
}